// Round 3
// baseline (395.113 us; speedup 1.0000x reference)
//
#include <hip/hip_runtime.h>
#include <math.h>

#define SEQ   168
#define BATCH 4096
#define NOUT  9

typedef short bf16x8 __attribute__((ext_vector_type(8)));
typedef float f32x4  __attribute__((ext_vector_type(4)));

#define MFMA(a,b,c) __builtin_amdgcn_mfma_f32_16x16x32_bf16((a),(b),(c),0,0,0)

static __device__ __forceinline__ unsigned short f2bf(float f){
    unsigned int u = __builtin_bit_cast(unsigned int, f);
    return (unsigned short)((u + 0x7fffu + ((u >> 16) & 1u)) >> 16);
}
static __device__ __forceinline__ float bf2f(unsigned short h){
    unsigned int u = ((unsigned int)h) << 16;
    return __builtin_bit_cast(float, u);
}
static __device__ __forceinline__ void splitf(float f, unsigned short& hi, unsigned short& lo){
    hi = f2bf(f);
    lo = f2bf(f - bf2f(hi));
}
static __device__ __forceinline__ float sigf(float x){
    x = fminf(fmaxf(x, -30.f), 30.f);
    return __builtin_amdgcn_rcpf(1.0f + __expf(-x));
}
static __device__ __forceinline__ float tanhf_(float x){
    x = fminf(fmaxf(x, -15.f), 15.f);
    float e = __expf(2.0f * x);
    return (e - 1.0f) * __builtin_amdgcn_rcpf(e + 1.0f);
}
static __device__ __forceinline__ bf16x8 ldfrag(const unsigned short* p){
    const uint4 q = *reinterpret_cast<const uint4*>(p);
    return __builtin_bit_cast(bf16x8, q);
}

// One persistent kernel: per tick t, layer0 does step t, layer1 does step t-1,
// head emits step t-2.  h0/h1 live in LDS as hi/lo bf16 planes in exactly the
// MFMA A-fragment layout ([row][k]); l0-feedback and l1-input share fragments.
__global__ __launch_bounds__(256, 1)
void lstm_fused(const float* __restrict__ x,
                const float* __restrict__ Wih0, const float* __restrict__ Whh0,
                const float* __restrict__ bih0, const float* __restrict__ bhh0,
                const float* __restrict__ Wih1, const float* __restrict__ Whh1,
                const float* __restrict__ bih1, const float* __restrict__ bhh1,
                const float* __restrict__ Wout, const float* __restrict__ bout,
                float* __restrict__ out)
{
    __shared__ __align__(16) unsigned short sXH[2][16][32],  sXL[2][16][32];
    __shared__ __align__(16) unsigned short sH0H[2][16][72], sH0L[2][16][72];
    __shared__ __align__(16) unsigned short sH1H[2][16][72], sH1L[2][16][72];

    const int tid = threadIdx.x;
    const int w   = tid >> 6;       // wave id -> unit group
    const int l   = tid & 63;
    const int lr  = l & 15;         // A row / D col lane
    const int g   = l >> 4;         // k-subgroup within fragment
    const int r0  = blockIdx.x * 16;
    const int cg  = w * 16 + lr;    // hidden unit [0,64)
    const int oc  = lr;             // head output column

    // ---------------- weights -> register fragments (hi/lo split) ----------------
    bf16x8 B0H[4][3], B0L[4][3];    // l0: ks0 = Wih0 (K=24 pad 32), ks1,2 = Whh0
    bf16x8 B1H[4][4], B1L[4][4];    // l1: ks0,1 = Wih1, ks2,3 = Whh1
    bf16x8 WoH[2], WoL[2];

    #pragma unroll
    for (int gt = 0; gt < 4; ++gt){
        const int c = gt * 64 + cg;
        bf16x8 bh = {0,0,0,0,0,0,0,0}, bl = {0,0,0,0,0,0,0,0};
        if (g < 3){
            const float* pw = &Wih0[c * 24 + g * 8];
            #pragma unroll
            for (int j = 0; j < 8; ++j){ unsigned short hh, ll; splitf(pw[j], hh, ll); bh[j]=(short)hh; bl[j]=(short)ll; }
        }
        B0H[gt][0] = bh; B0L[gt][0] = bl;
        #pragma unroll
        for (int ks = 0; ks < 2; ++ks){
            bf16x8 ch, cl;
            const float* pw = &Whh0[c * 64 + ks * 32 + g * 8];
            #pragma unroll
            for (int j = 0; j < 8; ++j){ unsigned short hh, ll; splitf(pw[j], hh, ll); ch[j]=(short)hh; cl[j]=(short)ll; }
            B0H[gt][1+ks] = ch; B0L[gt][1+ks] = cl;
        }
        #pragma unroll
        for (int ks = 0; ks < 2; ++ks){
            bf16x8 ch, cl;
            const float* pw = &Wih1[c * 64 + ks * 32 + g * 8];
            #pragma unroll
            for (int j = 0; j < 8; ++j){ unsigned short hh, ll; splitf(pw[j], hh, ll); ch[j]=(short)hh; cl[j]=(short)ll; }
            B1H[gt][ks] = ch; B1L[gt][ks] = cl;
        }
        #pragma unroll
        for (int ks = 0; ks < 2; ++ks){
            bf16x8 ch, cl;
            const float* pw = &Whh1[c * 64 + ks * 32 + g * 8];
            #pragma unroll
            for (int j = 0; j < 8; ++j){ unsigned short hh, ll; splitf(pw[j], hh, ll); ch[j]=(short)hh; cl[j]=(short)ll; }
            B1H[gt][2+ks] = ch; B1L[gt][2+ks] = cl;
        }
    }
    #pragma unroll
    for (int tt = 0; tt < 2; ++tt){
        bf16x8 bh = {0,0,0,0,0,0,0,0}, bl = {0,0,0,0,0,0,0,0};
        if (oc < NOUT){
            const float* pw = &Wout[oc * 64 + tt * 32 + g * 8];
            #pragma unroll
            for (int j = 0; j < 8; ++j){ unsigned short hh, ll; splitf(pw[j], hh, ll); bh[j]=(short)hh; bl[j]=(short)ll; }
        }
        WoH[tt] = bh; WoL[tt] = bl;
    }

    float b0[4], b1[4];
    #pragma unroll
    for (int gt = 0; gt < 4; ++gt){
        b0[gt] = bih0[gt*64 + cg] + bhh0[gt*64 + cg];
        b1[gt] = bih1[gt*64 + cg] + bhh1[gt*64 + cg];
    }
    const float bo0 = (oc < NOUT) ? bout[oc] : 0.f;

    // ---------------- zero LDS (also = initial h,c state and pad lanes) ----------
    for (int i = tid; i < 2*16*32/2; i += 256){
        ((unsigned int*)sXH)[i] = 0u; ((unsigned int*)sXL)[i] = 0u;
    }
    for (int i = tid; i < 2*16*72/2; i += 256){
        ((unsigned int*)sH0H)[i] = 0u; ((unsigned int*)sH0L)[i] = 0u;
        ((unsigned int*)sH1H)[i] = 0u; ((unsigned int*)sH1L)[i] = 0u;
    }
    __syncthreads();

    // stage x_0 into buffer 0
    if (tid < 96){
        const float4 v = *reinterpret_cast<const float4*>(&x[(size_t)r0 * 24 + tid * 4]);
        const int row = (tid * 4) / 24, col = (tid * 4) % 24;
        float vv[4] = {v.x, v.y, v.z, v.w};
        #pragma unroll
        for (int j = 0; j < 4; ++j){
            unsigned short hh, ll; splitf(vv[j], hh, ll);
            sXH[0][row][col + j] = hh; sXL[0][row][col + j] = ll;
        }
    }
    __syncthreads();

    float c0[4] = {0,0,0,0}, c1[4] = {0,0,0,0};

    int p = 0;
    for (int t = 0; t < SEQ + 2; ++t, p ^= 1){
        // ---- A fragments (pure b128 reads, no unpacking) ----
        const bf16x8 AxH = ldfrag(&sXH[p][lr][g*8]);
        const bf16x8 AxL = ldfrag(&sXL[p][lr][g*8]);
        bf16x8 A0H[2], A0L[2], A1H[2], A1L[2];
        #pragma unroll
        for (int ks = 0; ks < 2; ++ks){
            A0H[ks] = ldfrag(&sH0H[p][lr][ks*32 + g*8]);
            A0L[ks] = ldfrag(&sH0L[p][lr][ks*32 + g*8]);
            A1H[ks] = ldfrag(&sH1H[p][lr][ks*32 + g*8]);
            A1L[ks] = ldfrag(&sH1L[p][lr][ks*32 + g*8]);
        }

        // ---- prefetch next x tile (global -> regs, hidden under MFMAs) ----
        float4 pre;
        if (tid < 96){
            const int sn = (t + 1 < SEQ) ? (t + 1) : (SEQ - 1);
            pre = *reinterpret_cast<const float4*>(
                &x[((size_t)sn * BATCH + r0) * 24 + tid * 4]);
        }

        // ---- layer-0 gates: 36 MFMAs (step t) ----
        f32x4 a0[4];
        if (t < SEQ){
            #pragma unroll
            for (int gt = 0; gt < 4; ++gt){ f32x4 a = {b0[gt],b0[gt],b0[gt],b0[gt]}; a0[gt] = a; }
            #pragma unroll
            for (int gt = 0; gt < 4; ++gt) a0[gt] = MFMA(AxH, B0H[gt][0], a0[gt]);
            #pragma unroll
            for (int gt = 0; gt < 4; ++gt) a0[gt] = MFMA(AxH, B0L[gt][0], a0[gt]);
            #pragma unroll
            for (int gt = 0; gt < 4; ++gt) a0[gt] = MFMA(AxL, B0H[gt][0], a0[gt]);
            #pragma unroll
            for (int ks = 0; ks < 2; ++ks){
                #pragma unroll
                for (int gt = 0; gt < 4; ++gt) a0[gt] = MFMA(A0H[ks], B0H[gt][1+ks], a0[gt]);
                #pragma unroll
                for (int gt = 0; gt < 4; ++gt) a0[gt] = MFMA(A0H[ks], B0L[gt][1+ks], a0[gt]);
                #pragma unroll
                for (int gt = 0; gt < 4; ++gt) a0[gt] = MFMA(A0L[ks], B0H[gt][1+ks], a0[gt]);
            }
        }

        // ---- layer-1 gates: 48 MFMAs (step t-1; input h0_{t-1} = same A0 frags) ----
        f32x4 a1[4];
        const bool l1act = (t >= 1) && (t <= SEQ);
        if (l1act){
            #pragma unroll
            for (int gt = 0; gt < 4; ++gt){ f32x4 a = {b1[gt],b1[gt],b1[gt],b1[gt]}; a1[gt] = a; }
            #pragma unroll
            for (int ks = 0; ks < 2; ++ks){
                #pragma unroll
                for (int gt = 0; gt < 4; ++gt) a1[gt] = MFMA(A0H[ks], B1H[gt][ks], a1[gt]);
                #pragma unroll
                for (int gt = 0; gt < 4; ++gt) a1[gt] = MFMA(A0H[ks], B1L[gt][ks], a1[gt]);
                #pragma unroll
                for (int gt = 0; gt < 4; ++gt) a1[gt] = MFMA(A0L[ks], B1H[gt][ks], a1[gt]);
            }
            #pragma unroll
            for (int ks = 0; ks < 2; ++ks){
                #pragma unroll
                for (int gt = 0; gt < 4; ++gt) a1[gt] = MFMA(A1H[ks], B1H[gt][2+ks], a1[gt]);
                #pragma unroll
                for (int gt = 0; gt < 4; ++gt) a1[gt] = MFMA(A1H[ks], B1L[gt][2+ks], a1[gt]);
                #pragma unroll
                for (int gt = 0; gt < 4; ++gt) a1[gt] = MFMA(A1L[ks], B1H[gt][2+ks], a1[gt]);
            }
        }

        // ---- head MFMAs for step t-2 (reuses h1_{t-2} feedback frags), wave 0 ----
        f32x4 ha;
        const bool headact = (t >= 2) && (w == 0);
        if (headact){
            f32x4 a = {bo0, bo0, bo0, bo0}; ha = a;
            #pragma unroll
            for (int tt = 0; tt < 2; ++tt){
                ha = MFMA(A1H[tt], WoH[tt], ha);
                ha = MFMA(A1H[tt], WoL[tt], ha);
                ha = MFMA(A1L[tt], WoH[tt], ha);
            }
        }

        // ---- layer-0 nonlinearity -> h0_t planes (overlaps l1 MFMA drain) ----
        if (t < SEQ){
            #pragma unroll
            for (int i = 0; i < 4; ++i){
                const int R = g * 4 + i;
                const float ig = sigf(a0[0][i]);
                const float fg = sigf(a0[1][i]);
                const float gg = tanhf_(a0[2][i]);
                const float og = sigf(a0[3][i]);
                c0[i] = fg * c0[i] + ig * gg;
                const float h = og * tanhf_(c0[i]);
                unsigned short hh, ll; splitf(h, hh, ll);
                sH0H[p ^ 1][R][cg] = hh;
                sH0L[p ^ 1][R][cg] = ll;
            }
        }

        // ---- layer-1 nonlinearity -> h1_{t-1} planes ----
        if (l1act){
            #pragma unroll
            for (int i = 0; i < 4; ++i){
                const int R = g * 4 + i;
                const float ig = sigf(a1[0][i]);
                const float fg = sigf(a1[1][i]);
                const float gg = tanhf_(a1[2][i]);
                const float og = sigf(a1[3][i]);
                c1[i] = fg * c1[i] + ig * gg;
                const float h = og * tanhf_(c1[i]);
                unsigned short hh, ll; splitf(h, hh, ll);
                sH1H[p ^ 1][R][cg] = hh;
                sH1L[p ^ 1][R][cg] = ll;
            }
        }

        // ---- head stores for step t-2 ----
        if (headact && oc < NOUT){
            #pragma unroll
            for (int i = 0; i < 4; ++i)
                out[((size_t)(t - 2) * BATCH + r0 + g * 4 + i) * NOUT + oc] = ha[i];
        }

        // ---- write next x tile ----
        if (tid < 96){
            const int row = (tid * 4) / 24, col = (tid * 4) % 24;
            float vv[4] = {pre.x, pre.y, pre.z, pre.w};
            #pragma unroll
            for (int j = 0; j < 4; ++j){
                unsigned short hh, ll; splitf(vv[j], hh, ll);
                sXH[p ^ 1][row][col + j] = hh; sXL[p ^ 1][row][col + j] = ll;
            }
        }
        __syncthreads();
    }
}

extern "C" void kernel_launch(void* const* d_in, const int* in_sizes, int n_in,
                              void* d_out, int out_size, void* d_ws, size_t ws_size,
                              hipStream_t stream)
{
    const float* x    = (const float*)d_in[0];
    const float* Wih0 = (const float*)d_in[1];
    const float* Whh0 = (const float*)d_in[2];
    const float* bih0 = (const float*)d_in[3];
    const float* bhh0 = (const float*)d_in[4];
    const float* Wih1 = (const float*)d_in[5];
    const float* Whh1 = (const float*)d_in[6];
    const float* bih1 = (const float*)d_in[7];
    const float* bhh1 = (const float*)d_in[8];
    const float* Wout = (const float*)d_in[9];
    const float* bout = (const float*)d_in[10];
    float* out = (float*)d_out;

    lstm_fused<<<BATCH/16, 256, 0, stream>>>(x, Wih0, Whh0, bih0, bhh0,
                                             Wih1, Whh1, bih1, bhh1,
                                             Wout, bout, out);
}

// Round 4
// 252.016 us; speedup vs baseline: 1.5678x; 1.5678x over previous
//
#include <hip/hip_runtime.h>
#include <math.h>

#define SEQ   168
#define BATCH 4096
#define NOUT  9

typedef short bf16x8 __attribute__((ext_vector_type(8)));
typedef float f32x4  __attribute__((ext_vector_type(4)));

#define MFMA(a,b,c) __builtin_amdgcn_mfma_f32_16x16x32_bf16((a),(b),(c),0,0,0)

static __device__ __forceinline__ unsigned short f2bf(float f){   // RNE
    unsigned int u = __builtin_bit_cast(unsigned int, f);
    return (unsigned short)((u + 0x7fffu + ((u >> 16) & 1u)) >> 16);
}
static __device__ __forceinline__ float bf2f(unsigned short h){
    unsigned int u = ((unsigned int)h) << 16;
    return __builtin_bit_cast(float, u);
}
// hi = RNE(f), lo = trunc(f - hi): lo captures the full residual, total err ~2^-16 rel
static __device__ __forceinline__ void splitf(float f, unsigned short& hi, unsigned short& lo){
    hi = f2bf(f);
    float r = f - bf2f(hi);
    lo = (unsigned short)(__builtin_bit_cast(unsigned int, r) >> 16);
}
// clamp-free: e^-x -> inf gives rcp=0 (correct limit); no overflow hazards
static __device__ __forceinline__ float sigf(float x){
    return __builtin_amdgcn_rcpf(1.0f + __expf(-x));
}
// clamp-free tanh via e^{-2|x|} (always <= 1), sign restored by copysign
static __device__ __forceinline__ float tanhf_(float x){
    float ax = fabsf(x);
    float e  = __expf(-2.0f * ax);
    float t  = (1.0f - e) * __builtin_amdgcn_rcpf(1.0f + e);
    return copysignf(t, x);
}
static __device__ __forceinline__ bf16x8 ldfrag(const unsigned short* p){
    const uint4 q = *reinterpret_cast<const uint4*>(p);
    return __builtin_bit_cast(bf16x8, q);
}

// 512-thread blocks: waves 0-3 = layer0 (step t), waves 4-7 = layer1 (step t-1)
// + head (step t-2). h0/h1 as hi/lo bf16 planes in MFMA A-fragment layout,
// double-buffered; one barrier per tick. Each half holds only its own weights
// in registers -> no spill, 2 waves/SIMD of independent work.
__global__ __launch_bounds__(512, 2)
void lstm_fused(const float* __restrict__ x,
                const float* __restrict__ Wih0, const float* __restrict__ Whh0,
                const float* __restrict__ bih0, const float* __restrict__ bhh0,
                const float* __restrict__ Wih1, const float* __restrict__ Whh1,
                const float* __restrict__ bih1, const float* __restrict__ bhh1,
                const float* __restrict__ Wout, const float* __restrict__ bout,
                float* __restrict__ out)
{
    __shared__ __align__(16) unsigned short sXH[2][16][32],  sXL[2][16][32];
    __shared__ __align__(16) unsigned short sH0H[2][16][72], sH0L[2][16][72];
    __shared__ __align__(16) unsigned short sH1H[2][16][72], sH1L[2][16][72];

    const int tid  = threadIdx.x;
    const int half = tid >> 8;        // 0: layer0 waves, 1: layer1 waves
    const int w2   = (tid >> 6) & 3;  // unit group within half
    const int l    = tid & 63;
    const int lr   = l & 15;          // A row / D col lane
    const int g    = l >> 4;          // k subgroup
    const int r0   = blockIdx.x * 16;
    const int cg   = w2 * 16 + lr;    // hidden unit [0,64)

    // ---- zero LDS (initial h,c = 0; also K-pad lanes) ----
    for (int i = tid; i < (int)(2*16*32/2); i += 512){
        ((unsigned int*)sXH)[i] = 0u; ((unsigned int*)sXL)[i] = 0u;
    }
    for (int i = tid; i < (int)(2*16*72/2); i += 512){
        ((unsigned int*)sH0H)[i] = 0u; ((unsigned int*)sH0L)[i] = 0u;
        ((unsigned int*)sH1H)[i] = 0u; ((unsigned int*)sH1L)[i] = 0u;
    }
    __syncthreads();
    // ---- stage x_0 into buffer 0 ----
    if (tid < 96){
        const float4 v = *reinterpret_cast<const float4*>(&x[(size_t)r0 * 24 + tid * 4]);
        const int row = (tid * 4) / 24, col = (tid * 4) % 24;
        float vv[4] = {v.x, v.y, v.z, v.w};
        #pragma unroll
        for (int j = 0; j < 4; ++j){
            unsigned short hh, ll; splitf(vv[j], hh, ll);
            sXH[0][row][col + j] = hh; sXL[0][row][col + j] = ll;
        }
    }
    __syncthreads();

    if (half == 0){
        // ================= LAYER 0 waves =================
        bf16x8 B0H[4][3], B0L[4][3];   // ks0 = Wih0 (K=24 pad 32), ks1,2 = Whh0
        #pragma unroll
        for (int gt = 0; gt < 4; ++gt){
            const int c = gt * 64 + cg;
            bf16x8 bh = {0,0,0,0,0,0,0,0}, bl = {0,0,0,0,0,0,0,0};
            if (g < 3){
                const float* pw = &Wih0[c * 24 + g * 8];
                #pragma unroll
                for (int j = 0; j < 8; ++j){ unsigned short hh, ll; splitf(pw[j], hh, ll); bh[j]=(short)hh; bl[j]=(short)ll; }
            }
            B0H[gt][0] = bh; B0L[gt][0] = bl;
            #pragma unroll
            for (int ks = 0; ks < 2; ++ks){
                bf16x8 ch, cl;
                const float* pw = &Whh0[c * 64 + ks * 32 + g * 8];
                #pragma unroll
                for (int j = 0; j < 8; ++j){ unsigned short hh, ll; splitf(pw[j], hh, ll); ch[j]=(short)hh; cl[j]=(short)ll; }
                B0H[gt][1+ks] = ch; B0L[gt][1+ks] = cl;
            }
        }
        float b0[4];
        #pragma unroll
        for (int gt = 0; gt < 4; ++gt) b0[gt] = bih0[gt*64 + cg] + bhh0[gt*64 + cg];

        float c0[4] = {0,0,0,0};
        int p = 0;
        for (int t = 0; t < SEQ + 2; ++t, p ^= 1){
            // prefetch next x tile (clamped; content unused for t>=SEQ-1 writes)
            float4 pre;
            const int sn = (t + 1 < SEQ) ? (t + 1) : (SEQ - 1);
            if (tid < 96)
                pre = *reinterpret_cast<const float4*>(
                    &x[((size_t)sn * BATCH + r0) * 24 + tid * 4]);

            if (t < SEQ){
                const bf16x8 AxH = ldfrag(&sXH[p][lr][g*8]);
                const bf16x8 AxL = ldfrag(&sXL[p][lr][g*8]);
                bf16x8 A0H[2], A0L[2];
                #pragma unroll
                for (int ks = 0; ks < 2; ++ks){
                    A0H[ks] = ldfrag(&sH0H[p][lr][ks*32 + g*8]);
                    A0L[ks] = ldfrag(&sH0L[p][lr][ks*32 + g*8]);
                }
                f32x4 a0[4];
                #pragma unroll
                for (int gt = 0; gt < 4; ++gt){ f32x4 a = {b0[gt],b0[gt],b0[gt],b0[gt]}; a0[gt] = a; }
                #pragma unroll
                for (int gt = 0; gt < 4; ++gt) a0[gt] = MFMA(AxH, B0H[gt][0], a0[gt]);
                #pragma unroll
                for (int gt = 0; gt < 4; ++gt) a0[gt] = MFMA(AxH, B0L[gt][0], a0[gt]);
                #pragma unroll
                for (int gt = 0; gt < 4; ++gt) a0[gt] = MFMA(AxL, B0H[gt][0], a0[gt]);
                #pragma unroll
                for (int ks = 0; ks < 2; ++ks){
                    #pragma unroll
                    for (int gt = 0; gt < 4; ++gt) a0[gt] = MFMA(A0H[ks], B0H[gt][1+ks], a0[gt]);
                    #pragma unroll
                    for (int gt = 0; gt < 4; ++gt) a0[gt] = MFMA(A0H[ks], B0L[gt][1+ks], a0[gt]);
                    #pragma unroll
                    for (int gt = 0; gt < 4; ++gt) a0[gt] = MFMA(A0L[ks], B0H[gt][1+ks], a0[gt]);
                }
                #pragma unroll
                for (int i = 0; i < 4; ++i){
                    const int R = g * 4 + i;
                    const float ig = sigf(a0[0][i]);
                    const float fg = sigf(a0[1][i]);
                    const float gg = tanhf_(a0[2][i]);
                    const float og = sigf(a0[3][i]);
                    c0[i] = fg * c0[i] + ig * gg;
                    const float h = og * tanhf_(c0[i]);
                    unsigned short hh, ll; splitf(h, hh, ll);
                    sH0H[p ^ 1][R][cg] = hh;
                    sH0L[p ^ 1][R][cg] = ll;
                }
            }
            if (tid < 96){
                const int row = (tid * 4) / 24, col = (tid * 4) % 24;
                float vv[4] = {pre.x, pre.y, pre.z, pre.w};
                #pragma unroll
                for (int j = 0; j < 4; ++j){
                    unsigned short hh, ll; splitf(vv[j], hh, ll);
                    sXH[p ^ 1][row][col + j] = hh; sXL[p ^ 1][row][col + j] = ll;
                }
            }
            __syncthreads();
        }
    } else {
        // ================= LAYER 1 + head waves =================
        bf16x8 B1H[4][4], B1L[4][4];   // ks0,1 = Wih1 (h0 in), ks2,3 = Whh1 (h1 fb)
        #pragma unroll
        for (int gt = 0; gt < 4; ++gt){
            const int c = gt * 64 + cg;
            #pragma unroll
            for (int ks = 0; ks < 2; ++ks){
                bf16x8 ch, cl;
                const float* pw = &Wih1[c * 64 + ks * 32 + g * 8];
                #pragma unroll
                for (int j = 0; j < 8; ++j){ unsigned short hh, ll; splitf(pw[j], hh, ll); ch[j]=(short)hh; cl[j]=(short)ll; }
                B1H[gt][ks] = ch; B1L[gt][ks] = cl;
            }
            #pragma unroll
            for (int ks = 0; ks < 2; ++ks){
                bf16x8 ch, cl;
                const float* pw = &Whh1[c * 64 + ks * 32 + g * 8];
                #pragma unroll
                for (int j = 0; j < 8; ++j){ unsigned short hh, ll; splitf(pw[j], hh, ll); ch[j]=(short)hh; cl[j]=(short)ll; }
                B1H[gt][2+ks] = ch; B1L[gt][2+ks] = cl;
            }
        }
        const int oc = lr;             // head output column
        bf16x8 WoH[2], WoL[2];
        #pragma unroll
        for (int tt = 0; tt < 2; ++tt){
            bf16x8 bh = {0,0,0,0,0,0,0,0}, bl = {0,0,0,0,0,0,0,0};
            if (oc < NOUT){
                const float* pw = &Wout[oc * 64 + tt * 32 + g * 8];
                #pragma unroll
                for (int j = 0; j < 8; ++j){ unsigned short hh, ll; splitf(pw[j], hh, ll); bh[j]=(short)hh; bl[j]=(short)ll; }
            }
            WoH[tt] = bh; WoL[tt] = bl;
        }
        float b1[4];
        #pragma unroll
        for (int gt = 0; gt < 4; ++gt) b1[gt] = bih1[gt*64 + cg] + bhh1[gt*64 + cg];
        const float bo0 = (oc < NOUT) ? bout[oc] : 0.f;

        float c1[4] = {0,0,0,0};
        int p = 0;
        for (int t = 0; t < SEQ + 2; ++t, p ^= 1){
            if (t >= 1){
                bf16x8 A0H[2], A0L[2], A1H[2], A1L[2];
                #pragma unroll
                for (int ks = 0; ks < 2; ++ks){
                    A0H[ks] = ldfrag(&sH0H[p][lr][ks*32 + g*8]);
                    A0L[ks] = ldfrag(&sH0L[p][lr][ks*32 + g*8]);
                    A1H[ks] = ldfrag(&sH1H[p][lr][ks*32 + g*8]);
                    A1L[ks] = ldfrag(&sH1L[p][lr][ks*32 + g*8]);
                }

                // head for step t-2 (A1 frags hold h1_{t-2}), wave w2==0 only
                if (t >= 2 && w2 == 0){
                    f32x4 ha = {bo0, bo0, bo0, bo0};
                    #pragma unroll
                    for (int tt = 0; tt < 2; ++tt){
                        ha = MFMA(A1H[tt], WoH[tt], ha);
                        ha = MFMA(A1H[tt], WoL[tt], ha);
                        ha = MFMA(A1L[tt], WoH[tt], ha);
                    }
                    if (oc < NOUT){
                        #pragma unroll
                        for (int i = 0; i < 4; ++i)
                            out[((size_t)(t - 2) * BATCH + r0 + g*4 + i) * NOUT + oc] = ha[i];
                    }
                }

                if (t <= SEQ){
                    f32x4 a1[4];
                    #pragma unroll
                    for (int gt = 0; gt < 4; ++gt){ f32x4 a = {b1[gt],b1[gt],b1[gt],b1[gt]}; a1[gt] = a; }
                    #pragma unroll
                    for (int ks = 0; ks < 2; ++ks){
                        #pragma unroll
                        for (int gt = 0; gt < 4; ++gt) a1[gt] = MFMA(A0H[ks], B1H[gt][ks], a1[gt]);
                        #pragma unroll
                        for (int gt = 0; gt < 4; ++gt) a1[gt] = MFMA(A0H[ks], B1L[gt][ks], a1[gt]);
                        #pragma unroll
                        for (int gt = 0; gt < 4; ++gt) a1[gt] = MFMA(A0L[ks], B1H[gt][ks], a1[gt]);
                    }
                    #pragma unroll
                    for (int ks = 0; ks < 2; ++ks){
                        #pragma unroll
                        for (int gt = 0; gt < 4; ++gt) a1[gt] = MFMA(A1H[ks], B1H[gt][2+ks], a1[gt]);
                        #pragma unroll
                        for (int gt = 0; gt < 4; ++gt) a1[gt] = MFMA(A1H[ks], B1L[gt][2+ks], a1[gt]);
                        #pragma unroll
                        for (int gt = 0; gt < 4; ++gt) a1[gt] = MFMA(A1L[ks], B1H[gt][2+ks], a1[gt]);
                    }
                    #pragma unroll
                    for (int i = 0; i < 4; ++i){
                        const int R = g * 4 + i;
                        const float ig = sigf(a1[0][i]);
                        const float fg = sigf(a1[1][i]);
                        const float gg = tanhf_(a1[2][i]);
                        const float og = sigf(a1[3][i]);
                        c1[i] = fg * c1[i] + ig * gg;
                        const float h = og * tanhf_(c1[i]);
                        unsigned short hh, ll; splitf(h, hh, ll);
                        sH1H[p ^ 1][R][cg] = hh;
                        sH1L[p ^ 1][R][cg] = ll;
                    }
                }
            }
            __syncthreads();
        }
    }
}

extern "C" void kernel_launch(void* const* d_in, const int* in_sizes, int n_in,
                              void* d_out, int out_size, void* d_ws, size_t ws_size,
                              hipStream_t stream)
{
    const float* x    = (const float*)d_in[0];
    const float* Wih0 = (const float*)d_in[1];
    const float* Whh0 = (const float*)d_in[2];
    const float* bih0 = (const float*)d_in[3];
    const float* bhh0 = (const float*)d_in[4];
    const float* Wih1 = (const float*)d_in[5];
    const float* Whh1 = (const float*)d_in[6];
    const float* bih1 = (const float*)d_in[7];
    const float* bhh1 = (const float*)d_in[8];
    const float* Wout = (const float*)d_in[9];
    const float* bout = (const float*)d_in[10];
    float* out = (float*)d_out;

    lstm_fused<<<BATCH/16, 512, 0, stream>>>(x, Wih0, Whh0, bih0, bhh0,
                                             Wih1, Whh1, bih1, bhh1,
                                             Wout, bout, out);
}